// Round 7
// baseline (2471.089 us; speedup 1.0000x reference)
//
#include <hip/hip_runtime.h>
#include <hip/hip_bf16.h>

#define TT 1024
#define HH 128
#define G4 512

typedef float  f32x2 __attribute__((ext_vector_type(2)));
typedef float  f32x4v __attribute__((ext_vector_type(4)));
typedef short  s16x8 __attribute__((ext_vector_type(8)));
typedef int    i32x4 __attribute__((ext_vector_type(4)));
typedef unsigned int u32;
typedef unsigned short u16;

__device__ __forceinline__ float tanh_f(float x){ return 1.f - 2.f*__builtin_amdgcn_rcpf(1.f + __expf(2.f*x)); }

// pin weight pair into AGPRs (unified RF on gfx950; VALU reads AGPR src directly)
__device__ __forceinline__ void keepa(f32x2 &v){ asm volatile("" : "+a"(v)); }

__device__ __forceinline__ float dpp_mov(float v, const int ctrl){
    int t;
    switch (ctrl) {
      case 0x00: t = __builtin_amdgcn_update_dpp(0, __float_as_int(v), 0x00, 0xF, 0xF, true); break;
      case 0x55: t = __builtin_amdgcn_update_dpp(0, __float_as_int(v), 0x55, 0xF, 0xF, true); break;
      case 0xAA: t = __builtin_amdgcn_update_dpp(0, __float_as_int(v), 0xAA, 0xF, 0xF, true); break;
      case 0xFF: t = __builtin_amdgcn_update_dpp(0, __float_as_int(v), 0xFF, 0xF, 0xF, true); break;
      case 0x4E: t = __builtin_amdgcn_update_dpp(0, __float_as_int(v), 0x4E, 0xF, 0xF, true); break;
      default:   t = __builtin_amdgcn_update_dpp(0, __float_as_int(v), 0xB1, 0xF, 0xF, true); break;
    }
    return __int_as_float(t);
}
__device__ __forceinline__ float dpp_add(float v, const int ctrl){
    int t;
    switch (ctrl) {
      case 0xB1:  t = __builtin_amdgcn_update_dpp(0, __float_as_int(v), 0xB1, 0xF, 0xF, true); break;
      case 0x4E:  t = __builtin_amdgcn_update_dpp(0, __float_as_int(v), 0x4E, 0xF, 0xF, true); break;
      default:    t = __builtin_amdgcn_update_dpp(0, __float_as_int(v), 0x141, 0xF, 0xF, true); break;
    }
    return v + __int_as_float(t);
}
__device__ __forceinline__ float red8(float v){
    v = dpp_add(v, 0xB1);   // xor1
    v = dpp_add(v, 0x4E);   // xor2
    v = dpp_add(v, 0x141);  // xor4 (half-mirror; quads uniform after xor1/2)
    return v;
}

__device__ __forceinline__ u32 pack_bf16x2(float h){
    __hip_bfloat16 bh = __float2bfloat16(h);
    float hf = __bfloat162float(bh);
    __hip_bfloat16 bl = __float2bfloat16(h - hf);
    return (u32(__bfloat16_as_ushort(bh)) << 16) | u32(__bfloat16_as_ushort(bl));
}

// transpose-reduce across the 8 s-lanes: input acc[c]=(u0,u1) partials,
// output = this lane's component (c=s&3, u=s>>2) summed over all 8 slices.
__device__ __forceinline__ float xpose_red8(const f32x2 acc[4], const int s){
    const bool um = (s >> 2) & 1;
    float w4[4];
#pragma unroll
    for (int c = 0; c < 4; ++c) {
        const float send = um ? acc[c].x : acc[c].y;
        const float keep = um ? acc[c].y : acc[c].x;
        const float recv = __int_as_float(__builtin_amdgcn_ds_swizzle(__float_as_int(send), 0x101F)); // xor4
        w4[c] = keep + recv;
    }
    const bool b1 = (s >> 1) & 1;
    float u2[2];
#pragma unroll
    for (int e = 0; e < 2; ++e) {
        const float send = b1 ? w4[e] : w4[2 + e];
        const float keep = b1 ? w4[2 + e] : w4[e];
        u2[e] = keep + dpp_mov(send, 0x4E);   // xor2
    }
    const bool b0 = s & 1;
    const float send = b0 ? u2[0] : u2[1];
    const float keep = b0 ? u2[1] : u2[0];
    return keep + dpp_mov(send, 0xB1);        // xor1
}

// ---------------- prep: split W_ih1 into bf16 hi/lo planes ------------------
// PERMUTED row order (verified): plane row r holds original gate (r&3)*128+(r>>2).
__global__ void prep(const float* __restrict__ Wih1, u16* __restrict__ Bhi, u16* __restrict__ Blo)
{
    const int i = blockIdx.x * 256 + threadIdx.x;
    const int r = i >> 7;
    const int k = i & 127;
    const int g = (r & 3) * 128 + (r >> 2);
    const float w = Wih1[(size_t)g * HH + k];
    __hip_bfloat16 bh = __float2bfloat16(w);
    float hf = __bfloat162float(bh);
    __hip_bfloat16 bl = __float2bfloat16(w - hf);
    Bhi[i] = __bfloat16_as_ushort(bh);
    Blo[i] = __bfloat16_as_ushort(bl);
}

// ============================ layer 0 =======================================
__global__ __launch_bounds__(512, 2) void lstm0(
    const float* __restrict__ x, const float* __restrict__ Wih,
    const float* __restrict__ Whh, const float* __restrict__ bih,
    const float* __restrict__ bhh, u32* __restrict__ h0out)
{
    const int b   = blockIdx.x;
    const int tid = threadIdx.x;
    const int j0  = (tid >> 3) * 2;
    const int s   = tid & 7;

    __shared__ __align__(16) float xS[TT];
    __shared__ __align__(16) float hS[2][HH];

    int offs[4];
#pragma unroll
    for (int r = 0; r < 4; ++r) offs[r] = 16*s + 4*((r + (s>>1)) & 3);

    f32x2 w2[4][4][4];   // [gate c][r][e] -> 128 values, pinned to AGPRs
#pragma unroll
    for (int c = 0; c < 4; ++c)
#pragma unroll
        for (int r = 0; r < 4; ++r)
#pragma unroll
            for (int e = 0; e < 4; ++e) {
                const int k = offs[r] + e;
                w2[c][r][e] = (f32x2){ Whh[(size_t)(c*128 + j0    ) * HH + k],
                                       Whh[(size_t)(c*128 + j0 + 1) * HH + k] };
            }
#pragma unroll
    for (int c = 0; c < 4; ++c)
#pragma unroll
        for (int r = 0; r < 4; ++r)
#pragma unroll
            for (int e = 0; e < 4; ++e) keepa(w2[c][r][e]);

    // per-lane gate component: gate c=s&3, unit j = j0 + (s>>2)
    const int jl = j0 + (s >> 2);
    const int gl = (s & 3) * 128 + jl;
    const float b_lane  = bih[gl] + bhh[gl];
    const float wx_lane = Wih[gl];
    const bool  is_g = ((s & 3) == 2);
    const float Ac = is_g ? -2.f : 1.f;
    const float Bc = is_g ?  2.f : -1.f;
    const float Cc = is_g ?  1.f : 0.f;

    xS[tid]       = x[(size_t)b * TT + tid];
    xS[tid + 512] = x[(size_t)b * TT + tid + 512];
    if (tid < 256) ((float*)hS)[tid] = 0.f;
    float c1 = 0.f;
    __syncthreads();

    u32* hb = h0out + (size_t)b * TT * HH;

#pragma unroll 1
    for (int t = 0; t < TT; ++t) {
#pragma unroll
        for (int c = 0; c < 4; ++c)
#pragma unroll
            for (int r = 0; r < 4; ++r)
#pragma unroll
                for (int e = 0; e < 4; ++e) keepa(w2[c][r][e]);

        const float* hcur = hS[t & 1];
        f32x2 acc[4] = { {0.f,0.f}, {0.f,0.f}, {0.f,0.f}, {0.f,0.f} };
#pragma unroll
        for (int r = 0; r < 4; ++r) {
            const float4 hv = *(const float4*)(hcur + offs[r]);
            const float he[4] = { hv.x, hv.y, hv.z, hv.w };
#pragma unroll
            for (int e = 0; e < 4; ++e) {
                const f32x2 hb2 = (f32x2){ he[e], he[e] };
#pragma unroll
                for (int c = 0; c < 4; ++c)
                    acc[c] = __builtin_elementwise_fma(hb2, w2[c][r][e], acc[c]);
            }
        }
        const float V  = xpose_red8(acc, s);
        const float Vp = V + fmaf(xS[t], wx_lane, b_lane);
        const float a  = fmaf(Ac, __builtin_amdgcn_rcpf(1.f + __expf(Bc * Vp)), Cc);
        const float gi = dpp_mov(a, 0x00);
        const float gf = dpp_mov(a, 0x55);
        const float gg = dpp_mov(a, 0xAA);
        const float go = dpp_mov(a, 0xFF);
        c1 = fmaf(gf, c1, gi * gg);
        const float h = go * tanh_f(c1);
        if ((s & 3) == 0) {
            hS[(t + 1) & 1][jl] = h;
            hb[(size_t)t * HH + jl] = pack_bf16x2(h);
        }
        __syncthreads();
    }
}

// ============================ layer 1 + FC ==================================
__global__ __launch_bounds__(512, 2) void lstm1(
    const u32* __restrict__ h0in, const u16* __restrict__ Bhi,
    const u16* __restrict__ Blo,  const float* __restrict__ Whh,
    const float* __restrict__ bih, const float* __restrict__ bhh,
    const float* __restrict__ fcw, const float* __restrict__ fcb,
    float* __restrict__ out)
{
    const int b    = blockIdx.x;
    const int tid  = threadIdx.x;
    const int j0   = (tid >> 3) * 2;
    const int s    = tid & 7;
    const int wv   = tid >> 6;
    const int lane = tid & 63;

    __shared__ __align__(16) u16   hhS[32][HH];    // swizzled (k ^ ((r&7)<<4))
    __shared__ __align__(16) u16   hlS[32][HH];
    __shared__ __align__(16) float xgS[32 * G4];   // swizzled (g ^ ((i&7)<<2))
    __shared__ __align__(16) float hS[2][HH];
    __shared__ __align__(16) float fcP[2][8];

    int offs[4];
#pragma unroll
    for (int r = 0; r < 4; ++r) offs[r] = 16*s + 4*((r + (s>>1)) & 3);

    f32x2 w2[4][4][4];
#pragma unroll
    for (int c = 0; c < 4; ++c)
#pragma unroll
        for (int r = 0; r < 4; ++r)
#pragma unroll
            for (int e = 0; e < 4; ++e) {
                const int k = offs[r] + e;
                w2[c][r][e] = (f32x2){ Whh[(size_t)(c*128 + j0    ) * HH + k],
                                       Whh[(size_t)(c*128 + j0 + 1) * HH + k] };
            }
#pragma unroll
    for (int c = 0; c < 4; ++c)
#pragma unroll
        for (int r = 0; r < 4; ++r)
#pragma unroll
            for (int e = 0; e < 4; ++e) keepa(w2[c][r][e]);

    const int jl = j0 + (s >> 2);
    const int gl = (s & 3) * 128 + jl;
    const float b_lane   = bih[gl] + bhh[gl];
    const float fcw_lane = fcw[jl];
    const float fcbv = fcb[0];
    const bool  is_g = ((s & 3) == 2);
    const float Ac = is_g ? -2.f : 1.f;
    const float Bc = is_g ?  2.f : -1.f;
    const float Cc = is_g ?  1.f : 0.f;
    const int bp_addr = ((lane ^ 32) << 2);
    const int xpos = 4 * jl + (s & 3);

    // staging ids
    const int sr  = tid >> 4;
    const int sk8 = (tid & 15) * 8;
    // proj ids
    const int lr = lane & 15, lq = lane >> 4;

    if (tid < 256) ((float*)hS)[tid] = 0.f;
    float c1 = 0.f;
    __syncthreads();

    const u32* hbu = h0in + (size_t)b * TT * HH;
    float* ob = out + (size_t)b * TT;

#pragma unroll 1
    for (int t0 = 0; t0 < TT; t0 += 32) {
        // ---- stage h0 chunk as bf16 hi/lo planes ----
        {
            const int sw = (sr & 7) << 4;
#pragma unroll
            for (int g = 0; g < 2; ++g) {
                const i32x4 v = *(const i32x4*)&hbu[(size_t)(t0 + sr) * HH + sk8 + g*4];
                const u32 hi01 = __builtin_amdgcn_perm(v.y, v.x, 0x07060302u);
                const u32 hi23 = __builtin_amdgcn_perm(v.w, v.z, 0x07060302u);
                const u32 lo01 = __builtin_amdgcn_perm(v.y, v.x, 0x05040100u);
                const u32 lo23 = __builtin_amdgcn_perm(v.w, v.z, 0x05040100u);
                const int ks = (sk8 + g*4) ^ sw;
                *(u32*)&hhS[sr][ks]     = hi01;
                *(u32*)&hhS[sr][ks + 2] = hi23;
                *(u32*)&hlS[sr][ks]     = lo01;
                *(u32*)&hlS[sr][ks + 2] = lo23;
            }
        }
        __syncthreads();

        // ---- proj: xg^T = W_ih(permuted) * h0^T, 4 gate-tiles per wave ----
        {
#pragma unroll
            for (int gtl = 0; gtl < 4; ++gtl) {
                const int g16 = (wv * 4 + gtl) * 16;
                const u16* pAh = Bhi + (size_t)(g16 + lr) * HH + lq * 8;
                const u16* pAl = Blo + (size_t)(g16 + lr) * HH + lq * 8;
                f32x4v a0 = {0.f,0.f,0.f,0.f}, a1 = {0.f,0.f,0.f,0.f};
#pragma unroll
                for (int kk = 0; kk < 4; ++kk) {
                    const s16x8 Ah = *(const s16x8*)(pAh + kk * 32);
                    const s16x8 Al = *(const s16x8*)(pAl + kk * 32);
                    const int kb = (kk * 32 + lq * 8) ^ ((lr & 7) << 4);
                    const s16x8 Bh0 = *(const s16x8*)&hhS[lr][kb];
                    const s16x8 Bl0 = *(const s16x8*)&hlS[lr][kb];
                    const s16x8 Bh1 = *(const s16x8*)&hhS[16 + lr][kb];
                    const s16x8 Bl1 = *(const s16x8*)&hlS[16 + lr][kb];
                    a0 = __builtin_amdgcn_mfma_f32_16x16x32_bf16(Ah, Bh0, a0, 0, 0, 0);
                    a0 = __builtin_amdgcn_mfma_f32_16x16x32_bf16(Al, Bh0, a0, 0, 0, 0);
                    a0 = __builtin_amdgcn_mfma_f32_16x16x32_bf16(Ah, Bl0, a0, 0, 0, 0);
                    a1 = __builtin_amdgcn_mfma_f32_16x16x32_bf16(Ah, Bh1, a1, 0, 0, 0);
                    a1 = __builtin_amdgcn_mfma_f32_16x16x32_bf16(Al, Bh1, a1, 0, 0, 0);
                    a1 = __builtin_amdgcn_mfma_f32_16x16x32_bf16(Ah, Bl1, a1, 0, 0, 0);
                }
                const int gb  = g16 + lq * 4;
                const int swz = (lr & 7) << 2;
                *(float4*)&xgS[ lr       * G4 + (gb ^ swz)] = *(float4*)&a0;
                *(float4*)&xgS[(16 + lr) * G4 + (gb ^ swz)] = *(float4*)&a1;
            }
        }
        __syncthreads();

        // ---- 32 recurrent steps, 1 barrier each ----
#pragma unroll 1
        for (int i = 0; i < 32; ++i) {
            const int t = t0 + i;
            if (wv == 7 && t > 0) {     // deferred FC output for step t-1
                float v = (lane < 8) ? fcP[(t & 1) ^ 1][lane] : 0.f;
                v = red8(v);
                if (lane == 0) ob[t - 1] = v + fcbv;
            }
#pragma unroll
            for (int c = 0; c < 4; ++c)
#pragma unroll
                for (int r = 0; r < 4; ++r)
#pragma unroll
                    for (int e = 0; e < 4; ++e) keepa(w2[c][r][e]);

            const float* hcur = hS[t & 1];
            f32x2 acc[4] = { {0.f,0.f}, {0.f,0.f}, {0.f,0.f}, {0.f,0.f} };
#pragma unroll
            for (int r = 0; r < 4; ++r) {
                const float4 hv = *(const float4*)(hcur + offs[r]);
                const float he[4] = { hv.x, hv.y, hv.z, hv.w };
#pragma unroll
                for (int e = 0; e < 4; ++e) {
                    const f32x2 hb2 = (f32x2){ he[e], he[e] };
#pragma unroll
                    for (int c = 0; c < 4; ++c)
                        acc[c] = __builtin_elementwise_fma(hb2, w2[c][r][e], acc[c]);
                }
            }
            const float V = xpose_red8(acc, s);
            const int xswz = (i & 7) << 2;
            const float Vp = V + xgS[i * G4 + (xpos ^ xswz)] + b_lane;
            const float a  = fmaf(Ac, __builtin_amdgcn_rcpf(1.f + __expf(Bc * Vp)), Cc);
            const float gi = dpp_mov(a, 0x00);
            const float gf = dpp_mov(a, 0x55);
            const float gg = dpp_mov(a, 0xAA);
            const float go = dpp_mov(a, 0xFF);
            c1 = fmaf(gf, c1, gi * gg);
            const float h = go * tanh_f(c1);
            if ((s & 3) == 0) hS[(t + 1) & 1][jl] = h;
            float pf = ((s & 3) == 0) ? h * fcw_lane : 0.f;
            pf = red8(pf);
            pf += __int_as_float(__builtin_amdgcn_ds_swizzle(__float_as_int(pf), 0x201F)); // xor8
            pf += __int_as_float(__builtin_amdgcn_ds_swizzle(__float_as_int(pf), 0x401F)); // xor16
            pf += __int_as_float(__builtin_amdgcn_ds_bpermute(bp_addr, __float_as_int(pf))); // xor32
            if (lane == 0) fcP[t & 1][wv] = pf;
            __syncthreads();
        }
    }
    if (wv == 7) {
        float v = (lane < 8) ? fcP[(TT - 1) & 1][lane] : 0.f;
        v = red8(v);
        if (lane == 0) ob[TT - 1] = v + fcbv;
    }
}

extern "C" void kernel_launch(void* const* d_in, const int* in_sizes, int n_in,
                              void* d_out, int out_size, void* d_ws, size_t ws_size,
                              hipStream_t stream)
{
    const float* x    = (const float*)d_in[0];
    const float* Wih0 = (const float*)d_in[1];
    const float* Whh0 = (const float*)d_in[2];
    const float* bih0 = (const float*)d_in[3];
    const float* bhh0 = (const float*)d_in[4];
    const float* Wih1 = (const float*)d_in[5];
    const float* Whh1 = (const float*)d_in[6];
    const float* bih1 = (const float*)d_in[7];
    const float* bhh1 = (const float*)d_in[8];
    const float* fcw  = (const float*)d_in[9];
    const float* fcb  = (const float*)d_in[10];
    float* out = (float*)d_out;

    u32* h0  = (u32*)d_ws;                                        // 128 MiB
    u16* Bhi = (u16*)((char*)d_ws + (size_t)256 * TT * HH * 4);   // 128 KiB
    u16* Blo = Bhi + (size_t)G4 * HH;                             // 128 KiB

    prep <<<256, 256, 0, stream>>>(Wih1, Bhi, Blo);
    lstm0<<<256, 512, 0, stream>>>(x, Wih0, Whh0, bih0, bhh0, h0);
    lstm1<<<256, 512, 0, stream>>>(h0, Bhi, Blo, Whh1, bih1, bhh1, fcw, fcb, out);
}